// Round 16
// baseline (221.808 us; speedup 1.0000x reference)
//
#include <hip/hip_runtime.h>
#include <hip/hip_fp16.h>
#include <math.h>

#define NN 50000
#define FF 128
#define DD 64
#define EE 800000
#define GG 64
#define NEG_SLOPE 0.2f
#define EPSV 1e-16f

// CSR-build bucketing: coarse bucket = dst>>8 (256 nodes each)
#define NBKT 196                     // ceil(NN/256)
#define BCAP 5120                    // max edges/bucket (mean 4096, +16 sigma)
#define CHUNK 4096
#define EPB (CHUNK / 256)            // 16 edges per thread
#define NCH ((EE + CHUNK - 1) / CHUNK)   // 196

// ---------------- init: zero gcur/psum/ticket + projection vectors ----------
// blocks 0..2: wdad/wsas for layer b ; block 3: zero gcur + psum + ticket
__global__ __launch_bounds__(256) void init_k(
    const float* __restrict__ Wd0, const float* __restrict__ ad0,
    const float* __restrict__ Ws0, const float* __restrict__ as0,
    const float* __restrict__ Wd1, const float* __restrict__ ad1,
    const float* __restrict__ Ws1, const float* __restrict__ as1,
    const float* __restrict__ Wd2, const float* __restrict__ ad2,
    const float* __restrict__ Ws2, const float* __restrict__ as2,
    float* __restrict__ wdadAll, float* __restrict__ wsasAll,
    int* __restrict__ gcur, float* __restrict__ psum, int* __restrict__ ticket) {
    int b = blockIdx.x;
    int k = threadIdx.x;
    if (b == 3) {
        gcur[k] = 0;
        if (k == 0) *ticket = 0;
        for (int i = k; i < GG * DD; i += 256) psum[i] = 0.f;
        return;
    }
    const float* Wd = (b == 0) ? Wd0 : (b == 1) ? Wd1 : Wd2;
    const float* ad = (b == 0) ? ad0 : (b == 1) ? ad1 : ad2;
    const float* Ws = (b == 0) ? Ws0 : (b == 1) ? Ws1 : Ws2;
    const float* as = (b == 0) ? as0 : (b == 1) ? as1 : as2;
    int Din = (b == 0) ? FF : DD;
    if (k < Din) {
        float accd = 0.f, accs = 0.f;
        for (int d2 = 0; d2 < DD; ++d2) {
            accd += Wd[k * DD + d2] * ad[d2];
            accs += Ws[k * DD + d2] * as[d2];
        }
        wdadAll[b * FF + k] = accd;
        wsasAll[b * FF + k] = accs;
    }
}

// ---------------- CSR build ----------------

// Single global read pass: each thread holds its 16 edges in registers.
__global__ __launch_bounds__(256) void bin_k(const int* __restrict__ src,
                                             const int* __restrict__ dst,
                                             unsigned int* __restrict__ gbuf,
                                             int* __restrict__ gcur) {
    __shared__ unsigned int staged[CHUNK];     // 16 KB
    __shared__ int bc[256], bs[256], rb[256];
    int tid = threadIdx.x;
    bc[tid] = 0;
    __syncthreads();
    int base = blockIdx.x * CHUNK;
    int cnt = min(CHUNK, EE - base);
    unsigned int pe[EPB];
    int bk[EPB], lofs[EPB];
#pragma unroll
    for (int k = 0; k < EPB; ++k) {
        int i = tid + k * 256;                 // coalesced
        bk[k] = -1;
        if (i < cnt) {
            unsigned int s = (unsigned)src[base + i];
            unsigned int d = (unsigned)dst[base + i];
            pe[k] = (s << 16) | d;
            bk[k] = (int)(d >> 8);
            lofs[k] = atomicAdd(&bc[bk[k]], 1);
        }
    }
    __syncthreads();
    int v = bc[tid];
    bs[tid] = v;
    __syncthreads();
    for (int off = 1; off < 256; off <<= 1) {
        int t = (tid >= off) ? bs[tid - off] : 0;
        __syncthreads();
        bs[tid] += t;
        __syncthreads();
    }
    int excl = bs[tid] - v;
    __syncthreads();
    bs[tid] = excl;
    rb[tid] = atomicAdd(&gcur[tid], v);
    __syncthreads();
#pragma unroll
    for (int k = 0; k < EPB; ++k)
        if (bk[k] >= 0) staged[bs[bk[k]] + lofs[k]] = pe[k];
    __syncthreads();
    for (int i = tid; i < cnt; i += 256) {
        unsigned int p = staged[i];
        int b = (int)((p & 0xFFFFu) >> 8);
        gbuf[(size_t)b * BCAP + rb[b] + (i - bs[b])] = p;
    }
}

// merged bucket-prefix + hist + scan + rowstart + place; csr stored as ushort
__global__ __launch_bounds__(256) void build_k(const unsigned int* __restrict__ gbuf,
                                               const int* __restrict__ gcur,
                                               int* __restrict__ rowstart,
                                               unsigned short* __restrict__ csr) {
    __shared__ unsigned int st[BCAP];          // 20 KB
    __shared__ int hist[256], sc[256], cur[256];
    int tid = threadIdx.x, b = blockIdx.x;

    // in-block exclusive prefix over bucket totals -> bktoff for this block
    int gv = (tid < NBKT) ? gcur[tid] : 0;
    sc[tid] = gv;
    __syncthreads();
    for (int off = 1; off < 256; off <<= 1) {
        int t = (tid >= off) ? sc[tid - off] : 0;
        __syncthreads();
        sc[tid] += t;
        __syncthreads();
    }
    int bktoff = sc[b] - gcur[b];              // exclusive prefix at b
    if (b == 0 && tid == 0) rowstart[NN] = EE;
    __syncthreads();

    hist[tid] = 0;
    __syncthreads();
    int nb = gcur[b];
    const unsigned int* bb = gbuf + (size_t)b * BCAP;
    for (int i = tid; i < nb; i += 256) {
        unsigned int p = bb[i];
        st[i] = p;
        atomicAdd(&hist[p & 255u], 1);
    }
    __syncthreads();
    int v = hist[tid];
    sc[tid] = v;
    __syncthreads();
    for (int off = 1; off < 256; off <<= 1) {
        int t = (tid >= off) ? sc[tid - off] : 0;
        __syncthreads();
        sc[tid] += t;
        __syncthreads();
    }
    int rs = bktoff + sc[tid] - v;
    int node = b * 256 + tid;
    if (node < NN) rowstart[node] = rs;
    cur[tid] = rs;
    __syncthreads();
    for (int i = tid; i < nb; i += 256) {
        unsigned int p = st[i];
        int pos = atomicAdd(&cur[p & 255u], 1);
        csr[pos] = (unsigned short)(p >> 16);
    }
}

// ---------------- per-layer kernels ----------------

// xs(fp16) = h @ Ws ; es = h @ (Ws@a_s) ; ed = h @ (Wd@a_d)
// HIN: input h is fp16 (layers 1,2); else fp32 (layer 0 reads x).
template <int DIN, bool HIN>
__global__ __launch_bounds__(256, 4) void xform_k(
    const float* __restrict__ hf, const __half* __restrict__ hh,
    const float* __restrict__ Ws,
    const float* __restrict__ wsas, const float* __restrict__ wdad,
    __half* __restrict__ xs, float* __restrict__ es, float* __restrict__ ed,
    int n) {
    constexpr int PAD = DIN + 4;
    constexpr int XP = 68;
    __shared__ float hL[64 * PAD];
    int tid = threadIdx.x;
    int base = blockIdx.x * 64;

    {
        const int T4 = 64 * DIN / 4;               // groups of 4 elems
        int lim = n - base;
        lim = (lim > 64) ? T4 : lim * (DIN / 4);
        if constexpr (!HIN) {
            const float4* hg = reinterpret_cast<const float4*>(hf + (size_t)base * DIN);
            for (int i = tid; i < T4; i += 256) {
                float4 v = (i < lim) ? hg[i] : make_float4(0.f, 0.f, 0.f, 0.f);
                int r = i / (DIN / 4), c = i % (DIN / 4);
                *reinterpret_cast<float4*>(&hL[r * PAD + c * 4]) = v;
            }
        } else {
            const uint2* hg = reinterpret_cast<const uint2*>(hh + (size_t)base * DIN);
            for (int i = tid; i < T4; i += 256) {
                uint2 u = (i < lim) ? hg[i] : make_uint2(0u, 0u);
                float2 f01 = __half22float2(*reinterpret_cast<__half2*>(&u.x));
                float2 f23 = __half22float2(*reinterpret_cast<__half2*>(&u.y));
                int r = i / (DIN / 4), c = i % (DIN / 4);
                float* p = &hL[r * PAD + c * 4];
                p[0] = f01.x; p[1] = f01.y; p[2] = f23.x; p[3] = f23.y;
            }
        }
    }
    __syncthreads();

    int lane = tid & 63;
    int c0 = __builtin_amdgcn_readfirstlane((tid >> 6) << 4);
    float acc[16];
#pragma unroll
    for (int c = 0; c < 16; ++c) acc[c] = 0.f;
    float eacc = 0.f, dacc = 0.f;

    for (int k = 0; k < DIN; k += 4) {
        float4 hv = *reinterpret_cast<const float4*>(&hL[lane * PAD + k]);
        const float* w0 = Ws + (size_t)(k + 0) * DD + c0;
        const float* w1 = Ws + (size_t)(k + 1) * DD + c0;
        const float* w2 = Ws + (size_t)(k + 2) * DD + c0;
        const float* w3 = Ws + (size_t)(k + 3) * DD + c0;
#pragma unroll
        for (int c = 0; c < 16; ++c) {
            acc[c] = fmaf(hv.x, w0[c], acc[c]);
            acc[c] = fmaf(hv.y, w1[c], acc[c]);
            acc[c] = fmaf(hv.z, w2[c], acc[c]);
            acc[c] = fmaf(hv.w, w3[c], acc[c]);
        }
        eacc = fmaf(hv.x, wsas[k + 0], eacc); eacc = fmaf(hv.y, wsas[k + 1], eacc);
        eacc = fmaf(hv.z, wsas[k + 2], eacc); eacc = fmaf(hv.w, wsas[k + 3], eacc);
        dacc = fmaf(hv.x, wdad[k + 0], dacc); dacc = fmaf(hv.y, wdad[k + 1], dacc);
        dacc = fmaf(hv.z, wdad[k + 2], dacc); dacc = fmaf(hv.w, wdad[k + 3], dacc);
    }

    if ((tid >> 6) == 0 && base + lane < n) {
        es[base + lane] = eacc;
        ed[base + lane] = dacc;
    }
    __syncthreads();
    float* xsL = hL;
#pragma unroll
    for (int c = 0; c < 16; c += 4)
        *reinterpret_cast<float4*>(&xsL[lane * XP + c0 + c]) =
            make_float4(acc[c], acc[c + 1], acc[c + 2], acc[c + 3]);
    __syncthreads();
    {
        for (int i = tid; i < 64 * 16; i += 256) {
            int r = i >> 4, c4 = i & 15;
            if (base + r < n) {
                const float* f = &xsL[r * XP + c4 * 4];
                __half2 a = __floats2half2_rn(f[0], f[1]);
                __half2 b2 = __floats2half2_rn(f[2], f[3]);
                uint2 u;
                u.x = *reinterpret_cast<unsigned int*>(&a);
                u.y = *reinterpret_cast<unsigned int*>(&b2);
                *reinterpret_cast<uint2*>(xs + (size_t)(base + r) * DD + c4 * 4) = u;
            }
        }
    }
}

// one wave per destination node, single pass (shift-invariant softmax, no max).
// 8-wide row gather: slot=lane>>3 (8 edges/iter), fl=lane&7 (16B slice).
// Each gather instruction fetches 8 complete contiguous 128B rows (1KB/instr).
__global__ __launch_bounds__(256) void agg_k(
    const int* __restrict__ rowstart, const unsigned short* __restrict__ csr_src,
    const __half* __restrict__ xs, const float* __restrict__ es,
    const float* __restrict__ ed, const float* __restrict__ bias,
    __half* __restrict__ hout, int n, int relu) {
    int wid = (blockIdx.x * blockDim.x + threadIdx.x) >> 6;
    int lane = threadIdx.x & 63;
    if (wid >= n) return;
    int beg = rowstart[wid];
    int deg = rowstart[wid + 1] - beg;
    float edv = ed[wid];
    int slot = lane >> 3;       // 8 parallel edges
    int fl = lane & 7;          // 16B (8-half) feature slice

    float acc[8];
#pragma unroll
    for (int q = 0; q < 8; ++q) acc[q] = 0.f;
    float zl = 0.f;

    for (int c0 = 0; c0 < deg; c0 += 64) {
        int rem = min(64, deg - c0);
        int sv = 0;
        float pv = 0.f;
        if (lane < rem) {
            sv = (int)csr_src[beg + c0 + lane];
            float e = es[sv] + edv;
            e = (e >= 0.f) ? e : NEG_SLOPE * e;
            pv = __expf(e);
        }
        zl += pv;
        int iters = (rem + 7) >> 3;
#pragma unroll 2
        for (int c = 0; c < iters; ++c) {
            int j = c * 8 + slot;                  // < 64 always
            float p = __shfl(pv, j, 64);           // 0 for padding
            int s = __shfl(sv, j, 64);
            uint4 u = *reinterpret_cast<const uint4*>(xs + (size_t)s * DD + fl * 8);
            unsigned int uu[4] = {u.x, u.y, u.z, u.w};
#pragma unroll
            for (int q = 0; q < 4; ++q) {
                float2 f = __half22float2(*reinterpret_cast<const __half2*>(&uu[q]));
                acc[2 * q]     = fmaf(p, f.x, acc[2 * q]);
                acc[2 * q + 1] = fmaf(p, f.y, acc[2 * q + 1]);
            }
        }
    }

#pragma unroll
    for (int off = 32; off; off >>= 1) zl += __shfl_xor(zl, off, 64);
#pragma unroll
    for (int q = 0; q < 8; ++q) {
        acc[q] += __shfl_xor(acc[q], 8, 64);
        acc[q] += __shfl_xor(acc[q], 16, 64);
        acc[q] += __shfl_xor(acc[q], 32, 64);
    }

    if (slot == 0) {            // lanes 0..7; lane fl owns features [fl*8, fl*8+8)
        float inv = 1.f / (zl + EPSV);
        const float4* bp = reinterpret_cast<const float4*>(bias) + fl * 2;
        float4 b0 = bp[0], b1 = bp[1];
        float v0 = fmaf(acc[0], inv, b0.x), v1 = fmaf(acc[1], inv, b0.y);
        float v2 = fmaf(acc[2], inv, b0.z), v3 = fmaf(acc[3], inv, b0.w);
        float v4 = fmaf(acc[4], inv, b1.x), v5 = fmaf(acc[5], inv, b1.y);
        float v6 = fmaf(acc[6], inv, b1.z), v7 = fmaf(acc[7], inv, b1.w);
        if (relu) {
            v0 = fmaxf(v0, 0.f); v1 = fmaxf(v1, 0.f);
            v2 = fmaxf(v2, 0.f); v3 = fmaxf(v3, 0.f);
            v4 = fmaxf(v4, 0.f); v5 = fmaxf(v5, 0.f);
            v6 = fmaxf(v6, 0.f); v7 = fmaxf(v7, 0.f);
        }
        __half2 h0 = __floats2half2_rn(v0, v1);
        __half2 h1 = __floats2half2_rn(v2, v3);
        __half2 h2 = __floats2half2_rn(v4, v5);
        __half2 h3 = __floats2half2_rn(v6, v7);
        uint4 u;
        u.x = *reinterpret_cast<unsigned int*>(&h0);
        u.y = *reinterpret_cast<unsigned int*>(&h1);
        u.z = *reinterpret_cast<unsigned int*>(&h2);
        u.w = *reinterpret_cast<unsigned int*>(&h3);
        *reinterpret_cast<uint4*>(hout + (size_t)wid * DD + fl * 8) = u;
    }
}

// ---------------- pooling + fused final linear (last-block pattern) --------

__global__ __launch_bounds__(256) void pool_final_k(
    const __half* __restrict__ h, const int* __restrict__ batch,
    float* __restrict__ psum, int* __restrict__ ticket,
    const float* __restrict__ post_emb,
    const float* __restrict__ lin_w, const float* __restrict__ lin_b,
    float* __restrict__ out, int n, int nblocks) {
    int wid = (blockIdx.x * blockDim.x + threadIdx.x) >> 6;
    int lane = threadIdx.x & 63;
    int beg = wid * 16;
    if (beg < n) {
        int end = min(beg + 16, n);
        int curg = batch[beg];
        float acc = 0.f;
        for (int i = beg; i < end; ++i) {
            int g = batch[i];
            if (g != curg) {
                atomicAdd(&psum[curg * DD + lane], acc);
                acc = 0.f; curg = g;
            }
            acc += __half2float(h[(size_t)i * DD + lane]);
        }
        atomicAdd(&psum[curg * DD + lane], acc);
    }

    // last-block runs the final linear
    __threadfence();
    __syncthreads();
    __shared__ int isLast;
    if (threadIdx.x == 0)
        isLast = (atomicAdd(ticket, 1) == nblocks - 1);
    __syncthreads();
    if (!isLast) return;
    __threadfence();

    __shared__ int sL[GG + 1];
    int r = threadIdx.x;
    if (r <= GG) {
        int lo = 0, hi = NN;
        while (lo < hi) {
            int m = (lo + hi) >> 1;
            if (batch[m] < r) lo = m + 1; else hi = m;
        }
        sL[r] = lo;
    }
    __syncthreads();
    if (r >= 2 * GG) return;
    float o0 = 0.f, o1 = 0.f;
    if (r < GG) {
        float c = fmaxf((float)(sL[r + 1] - sL[r]), 1.f);
        float inv = 1.f / c;
        for (int d2 = 0; d2 < DD; ++d2) {
            float v = psum[r * DD + d2] * inv;
            o0 = fmaf(v, lin_w[d2 * 2 + 0], o0);
            o1 = fmaf(v, lin_w[d2 * 2 + 1], o1);
        }
    } else {
        const float* pe = post_emb + (size_t)(r - GG) * DD;
        for (int d2 = 0; d2 < DD; ++d2) {
            float v = pe[d2];
            o0 = fmaf(v, lin_w[d2 * 2 + 0], o0);
            o1 = fmaf(v, lin_w[d2 * 2 + 1], o1);
        }
    }
    out[r * 2 + 0] = o0 + lin_b[0];
    out[r * 2 + 1] = o1 + lin_b[1];
}

// ---------------- host ----------------

extern "C" void kernel_launch(void* const* d_in, const int* in_sizes, int n_in,
                              void* d_out, int out_size, void* d_ws, size_t ws_size,
                              hipStream_t stream) {
    const float* x        = (const float*)d_in[0];
    const int*   ei       = (const int*)d_in[1];
    const int*   src      = ei;
    const int*   dst      = ei + EE;
    const int*   batch    = (const int*)d_in[2];
    const float* post_emb = (const float*)d_in[3];
    const float* Ws[3] = {(const float*)d_in[4],  (const float*)d_in[9],  (const float*)d_in[14]};
    const float* Wd[3] = {(const float*)d_in[5],  (const float*)d_in[10], (const float*)d_in[15]};
    const float* av[3] = {(const float*)d_in[6],  (const float*)d_in[11], (const float*)d_in[16]};
    const float* ad[3] = {(const float*)d_in[7],  (const float*)d_in[12], (const float*)d_in[17]};
    const float* bb[3] = {(const float*)d_in[8],  (const float*)d_in[13], (const float*)d_in[18]};
    const float* lin_w = (const float*)d_in[19];
    const float* lin_b = (const float*)d_in[20];
    float* outp = (float*)d_out;

    char* w = (char*)d_ws;
    size_t off = 0;
    auto alloc = [&](size_t bytes) -> char* {
        char* p = w + off;
        off += (bytes + 255) & ~(size_t)255;
        return p;
    };
    __half*         xs       = (__half*)alloc((size_t)NN * DD * 2);
    __half*         h16      = (__half*)alloc((size_t)NN * DD * 2);
    float*          es       = (float*)alloc((size_t)NN * 4);
    float*          ed       = (float*)alloc((size_t)NN * 4);
    int*            rowstart = (int*)alloc((size_t)(NN + 1) * 4);
    unsigned short* csr      = (unsigned short*)alloc((size_t)EE * 2);
    float*          wdadAll  = (float*)alloc(3 * FF * 4);
    float*          wsasAll  = (float*)alloc(3 * FF * 4);
    float*          psum     = (float*)alloc((size_t)GG * DD * 4);
    unsigned int*   gbuf     = (unsigned int*)alloc((size_t)NBKT * BCAP * 4);
    int*            gcur     = (int*)alloc(256 * 4);
    int*            ticket   = (int*)alloc(256);

    // ---- init (zeroing + projection vectors) ----
    init_k<<<4, 256, 0, stream>>>(Wd[0], ad[0], Ws[0], av[0],
                                  Wd[1], ad[1], Ws[1], av[1],
                                  Wd[2], ad[2], Ws[2], av[2],
                                  wdadAll, wsasAll, gcur, psum, ticket);

    // ---- CSR build: bin (single-read) -> merged build ----
    bin_k<<<NCH, 256, 0, stream>>>(src, dst, gbuf, gcur);
    build_k<<<NBKT, 256, 0, stream>>>(gbuf, gcur, rowstart, csr);

    // ---- 3 GAT layers ----
    const int XB = (NN + 63) / 64;        // 782 blocks: 64 rows per block
    for (int l = 0; l < 3; ++l) {
        if (l == 0)
            xform_k<FF, false><<<XB, 256, 0, stream>>>(x, nullptr, Ws[l],
                                                       wsasAll + l * FF, wdadAll + l * FF,
                                                       xs, es, ed, NN);
        else
            xform_k<DD, true><<<XB, 256, 0, stream>>>(nullptr, h16, Ws[l],
                                                      wsasAll + l * FF, wdadAll + l * FF,
                                                      xs, es, ed, NN);
        agg_k<<<(NN * 64 + 255) / 256, 256, 0, stream>>>(rowstart, csr, xs, es, ed,
                                                         bb[l], h16, NN, (l < 2) ? 1 : 0);
    }

    // ---- pooling + fused final linear ----
    int pblocks = ((NN + 15) / 16 * 64 + 255) / 256;   // 782
    pool_final_k<<<pblocks, 256, 0, stream>>>(h16, batch, psum, ticket,
                                              post_emb, lin_w, lin_b, outp, NN, pblocks);
}

// Round 17
// 176.536 us; speedup vs baseline: 1.2564x; 1.2564x over previous
//
#include <hip/hip_runtime.h>
#include <hip/hip_fp16.h>
#include <math.h>

#define NN 50000
#define FF 128
#define DD 64
#define EE 800000
#define GG 64
#define NEG_SLOPE 0.2f
#define EPSV 1e-16f

// CSR-build bucketing: coarse bucket = dst>>8 (256 nodes each)
#define NBKT 196                     // ceil(NN/256)
#define BCAP 5120                    // max edges/bucket (mean 4096, +16 sigma)
#define CHUNK 4096
#define EPB (CHUNK / 256)            // 16 edges per thread
#define NCH ((EE + CHUNK - 1) / CHUNK)   // 196

// ---------------- init: zero gcur/psum + projection vectors ----------------
// blocks 0..2: wdad/wsas for layer b ; block 3: zero gcur + psum
__global__ __launch_bounds__(256) void init_k(
    const float* __restrict__ Wd0, const float* __restrict__ ad0,
    const float* __restrict__ Ws0, const float* __restrict__ as0,
    const float* __restrict__ Wd1, const float* __restrict__ ad1,
    const float* __restrict__ Ws1, const float* __restrict__ as1,
    const float* __restrict__ Wd2, const float* __restrict__ ad2,
    const float* __restrict__ Ws2, const float* __restrict__ as2,
    float* __restrict__ wdadAll, float* __restrict__ wsasAll,
    int* __restrict__ gcur, float* __restrict__ psum) {
    int b = blockIdx.x;
    int k = threadIdx.x;
    if (b == 3) {
        gcur[k] = 0;
        for (int i = k; i < GG * DD; i += 256) psum[i] = 0.f;
        return;
    }
    const float* Wd = (b == 0) ? Wd0 : (b == 1) ? Wd1 : Wd2;
    const float* ad = (b == 0) ? ad0 : (b == 1) ? ad1 : ad2;
    const float* Ws = (b == 0) ? Ws0 : (b == 1) ? Ws1 : Ws2;
    const float* as = (b == 0) ? as0 : (b == 1) ? as1 : as2;
    int Din = (b == 0) ? FF : DD;
    if (k < Din) {
        float accd = 0.f, accs = 0.f;
        for (int d2 = 0; d2 < DD; ++d2) {
            accd += Wd[k * DD + d2] * ad[d2];
            accs += Ws[k * DD + d2] * as[d2];
        }
        wdadAll[b * FF + k] = accd;
        wsasAll[b * FF + k] = accs;
    }
}

// ---------------- CSR build ----------------

// Single global read pass: each thread holds its 16 edges in registers.
__global__ __launch_bounds__(256) void bin_k(const int* __restrict__ src,
                                             const int* __restrict__ dst,
                                             unsigned int* __restrict__ gbuf,
                                             int* __restrict__ gcur) {
    __shared__ unsigned int staged[CHUNK];     // 16 KB
    __shared__ int bc[256], bs[256], rb[256];
    int tid = threadIdx.x;
    bc[tid] = 0;
    __syncthreads();
    int base = blockIdx.x * CHUNK;
    int cnt = min(CHUNK, EE - base);
    unsigned int pe[EPB];
    int bk[EPB], lofs[EPB];
#pragma unroll
    for (int k = 0; k < EPB; ++k) {
        int i = tid + k * 256;                 // coalesced
        bk[k] = -1;
        if (i < cnt) {
            unsigned int s = (unsigned)src[base + i];
            unsigned int d = (unsigned)dst[base + i];
            pe[k] = (s << 16) | d;
            bk[k] = (int)(d >> 8);
            lofs[k] = atomicAdd(&bc[bk[k]], 1);
        }
    }
    __syncthreads();
    int v = bc[tid];
    bs[tid] = v;
    __syncthreads();
    for (int off = 1; off < 256; off <<= 1) {
        int t = (tid >= off) ? bs[tid - off] : 0;
        __syncthreads();
        bs[tid] += t;
        __syncthreads();
    }
    int excl = bs[tid] - v;
    __syncthreads();
    bs[tid] = excl;
    rb[tid] = atomicAdd(&gcur[tid], v);
    __syncthreads();
#pragma unroll
    for (int k = 0; k < EPB; ++k)
        if (bk[k] >= 0) staged[bs[bk[k]] + lofs[k]] = pe[k];
    __syncthreads();
    for (int i = tid; i < cnt; i += 256) {
        unsigned int p = staged[i];
        int b = (int)((p & 0xFFFFu) >> 8);
        gbuf[(size_t)b * BCAP + rb[b] + (i - bs[b])] = p;
    }
}

// merged bucket-prefix + hist + scan + rowstart + place; csr stored as ushort
__global__ __launch_bounds__(256) void build_k(const unsigned int* __restrict__ gbuf,
                                               const int* __restrict__ gcur,
                                               int* __restrict__ rowstart,
                                               unsigned short* __restrict__ csr) {
    __shared__ unsigned int st[BCAP];          // 20 KB
    __shared__ int hist[256], sc[256], cur[256];
    int tid = threadIdx.x, b = blockIdx.x;

    // in-block exclusive prefix over bucket totals -> bktoff for this block
    int gv = (tid < NBKT) ? gcur[tid] : 0;
    sc[tid] = gv;
    __syncthreads();
    for (int off = 1; off < 256; off <<= 1) {
        int t = (tid >= off) ? sc[tid - off] : 0;
        __syncthreads();
        sc[tid] += t;
        __syncthreads();
    }
    int bktoff = sc[b] - gcur[b];              // exclusive prefix at b
    if (b == 0 && tid == 0) rowstart[NN] = EE;
    __syncthreads();

    hist[tid] = 0;
    __syncthreads();
    int nb = gcur[b];
    const unsigned int* bb = gbuf + (size_t)b * BCAP;
    for (int i = tid; i < nb; i += 256) {
        unsigned int p = bb[i];
        st[i] = p;
        atomicAdd(&hist[p & 255u], 1);
    }
    __syncthreads();
    int v = hist[tid];
    sc[tid] = v;
    __syncthreads();
    for (int off = 1; off < 256; off <<= 1) {
        int t = (tid >= off) ? sc[tid - off] : 0;
        __syncthreads();
        sc[tid] += t;
        __syncthreads();
    }
    int rs = bktoff + sc[tid] - v;
    int node = b * 256 + tid;
    if (node < NN) rowstart[node] = rs;
    cur[tid] = rs;
    __syncthreads();
    for (int i = tid; i < nb; i += 256) {
        unsigned int p = st[i];
        int pos = atomicAdd(&cur[p & 255u], 1);
        csr[pos] = (unsigned short)(p >> 16);
    }
}

// ---------------- per-layer kernels ----------------

// xs(fp16) = h @ Ws ; es = h @ (Ws@a_s) ; ed = h @ (Wd@a_d)
// HIN: input h is fp16 (layers 1,2); else fp32 (layer 0 reads x).
template <int DIN, bool HIN>
__global__ __launch_bounds__(256, 4) void xform_k(
    const float* __restrict__ hf, const __half* __restrict__ hh,
    const float* __restrict__ Ws,
    const float* __restrict__ wsas, const float* __restrict__ wdad,
    __half* __restrict__ xs, float* __restrict__ es, float* __restrict__ ed,
    int n) {
    constexpr int PAD = DIN + 4;
    constexpr int XP = 68;
    __shared__ float hL[64 * PAD];
    int tid = threadIdx.x;
    int base = blockIdx.x * 64;

    {
        const int T4 = 64 * DIN / 4;               // groups of 4 elems
        int lim = n - base;
        lim = (lim > 64) ? T4 : lim * (DIN / 4);
        if constexpr (!HIN) {
            const float4* hg = reinterpret_cast<const float4*>(hf + (size_t)base * DIN);
            for (int i = tid; i < T4; i += 256) {
                float4 v = (i < lim) ? hg[i] : make_float4(0.f, 0.f, 0.f, 0.f);
                int r = i / (DIN / 4), c = i % (DIN / 4);
                *reinterpret_cast<float4*>(&hL[r * PAD + c * 4]) = v;
            }
        } else {
            const uint2* hg = reinterpret_cast<const uint2*>(hh + (size_t)base * DIN);
            for (int i = tid; i < T4; i += 256) {
                uint2 u = (i < lim) ? hg[i] : make_uint2(0u, 0u);
                float2 f01 = __half22float2(*reinterpret_cast<__half2*>(&u.x));
                float2 f23 = __half22float2(*reinterpret_cast<__half2*>(&u.y));
                int r = i / (DIN / 4), c = i % (DIN / 4);
                float* p = &hL[r * PAD + c * 4];
                p[0] = f01.x; p[1] = f01.y; p[2] = f23.x; p[3] = f23.y;
            }
        }
    }
    __syncthreads();

    int lane = tid & 63;
    int c0 = __builtin_amdgcn_readfirstlane((tid >> 6) << 4);
    float acc[16];
#pragma unroll
    for (int c = 0; c < 16; ++c) acc[c] = 0.f;
    float eacc = 0.f, dacc = 0.f;

    for (int k = 0; k < DIN; k += 4) {
        float4 hv = *reinterpret_cast<const float4*>(&hL[lane * PAD + k]);
        const float* w0 = Ws + (size_t)(k + 0) * DD + c0;
        const float* w1 = Ws + (size_t)(k + 1) * DD + c0;
        const float* w2 = Ws + (size_t)(k + 2) * DD + c0;
        const float* w3 = Ws + (size_t)(k + 3) * DD + c0;
#pragma unroll
        for (int c = 0; c < 16; ++c) {
            acc[c] = fmaf(hv.x, w0[c], acc[c]);
            acc[c] = fmaf(hv.y, w1[c], acc[c]);
            acc[c] = fmaf(hv.z, w2[c], acc[c]);
            acc[c] = fmaf(hv.w, w3[c], acc[c]);
        }
        eacc = fmaf(hv.x, wsas[k + 0], eacc); eacc = fmaf(hv.y, wsas[k + 1], eacc);
        eacc = fmaf(hv.z, wsas[k + 2], eacc); eacc = fmaf(hv.w, wsas[k + 3], eacc);
        dacc = fmaf(hv.x, wdad[k + 0], dacc); dacc = fmaf(hv.y, wdad[k + 1], dacc);
        dacc = fmaf(hv.z, wdad[k + 2], dacc); dacc = fmaf(hv.w, wdad[k + 3], dacc);
    }

    if ((tid >> 6) == 0 && base + lane < n) {
        es[base + lane] = eacc;
        ed[base + lane] = dacc;
    }
    __syncthreads();
    float* xsL = hL;
#pragma unroll
    for (int c = 0; c < 16; c += 4)
        *reinterpret_cast<float4*>(&xsL[lane * XP + c0 + c]) =
            make_float4(acc[c], acc[c + 1], acc[c + 2], acc[c + 3]);
    __syncthreads();
    {
        for (int i = tid; i < 64 * 16; i += 256) {
            int r = i >> 4, c4 = i & 15;
            if (base + r < n) {
                const float* f = &xsL[r * XP + c4 * 4];
                __half2 a = __floats2half2_rn(f[0], f[1]);
                __half2 b2 = __floats2half2_rn(f[2], f[3]);
                uint2 u;
                u.x = *reinterpret_cast<unsigned int*>(&a);
                u.y = *reinterpret_cast<unsigned int*>(&b2);
                *reinterpret_cast<uint2*>(xs + (size_t)(base + r) * DD + c4 * 4) = u;
            }
        }
    }
}

// one wave per destination node, single pass (shift-invariant softmax, no max).
// 8-wide row gather: slot=lane>>3 (8 edges/iter), fl=lane&7 (16B slice).
// Each gather instruction fetches 8 complete contiguous 128B rows (1KB/instr).
__global__ __launch_bounds__(256) void agg_k(
    const int* __restrict__ rowstart, const unsigned short* __restrict__ csr_src,
    const __half* __restrict__ xs, const float* __restrict__ es,
    const float* __restrict__ ed, const float* __restrict__ bias,
    __half* __restrict__ hout, int n, int relu) {
    int wid = (blockIdx.x * blockDim.x + threadIdx.x) >> 6;
    int lane = threadIdx.x & 63;
    if (wid >= n) return;
    int beg = rowstart[wid];
    int deg = rowstart[wid + 1] - beg;
    float edv = ed[wid];
    int slot = lane >> 3;       // 8 parallel edges
    int fl = lane & 7;          // 16B (8-half) feature slice

    float acc[8];
#pragma unroll
    for (int q = 0; q < 8; ++q) acc[q] = 0.f;
    float zl = 0.f;

    for (int c0 = 0; c0 < deg; c0 += 64) {
        int rem = min(64, deg - c0);
        int sv = 0;
        float pv = 0.f;
        if (lane < rem) {
            sv = (int)csr_src[beg + c0 + lane];
            float e = es[sv] + edv;
            e = (e >= 0.f) ? e : NEG_SLOPE * e;
            pv = __expf(e);
        }
        zl += pv;
        int iters = (rem + 7) >> 3;
#pragma unroll 2
        for (int c = 0; c < iters; ++c) {
            int j = c * 8 + slot;                  // < 64 always
            float p = __shfl(pv, j, 64);           // 0 for padding
            int s = __shfl(sv, j, 64);
            uint4 u = *reinterpret_cast<const uint4*>(xs + (size_t)s * DD + fl * 8);
            unsigned int uu[4] = {u.x, u.y, u.z, u.w};
#pragma unroll
            for (int q = 0; q < 4; ++q) {
                float2 f = __half22float2(*reinterpret_cast<const __half2*>(&uu[q]));
                acc[2 * q]     = fmaf(p, f.x, acc[2 * q]);
                acc[2 * q + 1] = fmaf(p, f.y, acc[2 * q + 1]);
            }
        }
    }

#pragma unroll
    for (int off = 32; off; off >>= 1) zl += __shfl_xor(zl, off, 64);
#pragma unroll
    for (int q = 0; q < 8; ++q) {
        acc[q] += __shfl_xor(acc[q], 8, 64);
        acc[q] += __shfl_xor(acc[q], 16, 64);
        acc[q] += __shfl_xor(acc[q], 32, 64);
    }

    if (slot == 0) {            // lanes 0..7; lane fl owns features [fl*8, fl*8+8)
        float inv = 1.f / (zl + EPSV);
        const float4* bp = reinterpret_cast<const float4*>(bias) + fl * 2;
        float4 b0 = bp[0], b1 = bp[1];
        float v0 = fmaf(acc[0], inv, b0.x), v1 = fmaf(acc[1], inv, b0.y);
        float v2 = fmaf(acc[2], inv, b0.z), v3 = fmaf(acc[3], inv, b0.w);
        float v4 = fmaf(acc[4], inv, b1.x), v5 = fmaf(acc[5], inv, b1.y);
        float v6 = fmaf(acc[6], inv, b1.z), v7 = fmaf(acc[7], inv, b1.w);
        if (relu) {
            v0 = fmaxf(v0, 0.f); v1 = fmaxf(v1, 0.f);
            v2 = fmaxf(v2, 0.f); v3 = fmaxf(v3, 0.f);
            v4 = fmaxf(v4, 0.f); v5 = fmaxf(v5, 0.f);
            v6 = fmaxf(v6, 0.f); v7 = fmaxf(v7, 0.f);
        }
        __half2 h0 = __floats2half2_rn(v0, v1);
        __half2 h1 = __floats2half2_rn(v2, v3);
        __half2 h2 = __floats2half2_rn(v4, v5);
        __half2 h3 = __floats2half2_rn(v6, v7);
        uint4 u;
        u.x = *reinterpret_cast<unsigned int*>(&h0);
        u.y = *reinterpret_cast<unsigned int*>(&h1);
        u.z = *reinterpret_cast<unsigned int*>(&h2);
        u.w = *reinterpret_cast<unsigned int*>(&h3);
        *reinterpret_cast<uint4*>(hout + (size_t)wid * DD + fl * 8) = u;
    }
}

// ---------------- pooling + final linear ----------------

__global__ __launch_bounds__(256) void pool_k(
    const __half* __restrict__ h, const int* __restrict__ batch,
    float* __restrict__ psum, int n) {
    int wid = (blockIdx.x * blockDim.x + threadIdx.x) >> 6;
    int lane = threadIdx.x & 63;
    int beg = wid * 16;
    if (beg >= n) return;
    int end = min(beg + 16, n);
    int curg = batch[beg];
    float acc = 0.f;
    for (int i = beg; i < end; ++i) {
        int g = batch[i];
        if (g != curg) {
            atomicAdd(&psum[curg * DD + lane], acc);
            acc = 0.f; curg = g;
        }
        acc += __half2float(h[(size_t)i * DD + lane]);
    }
    atomicAdd(&psum[curg * DD + lane], acc);
}

__global__ void final_k(const float* __restrict__ psum, const int* __restrict__ batch,
                        const float* __restrict__ post_emb,
                        const float* __restrict__ lin_w, const float* __restrict__ lin_b,
                        float* __restrict__ out) {
    __shared__ int sL[GG + 1];
    int r = threadIdx.x;
    if (r <= GG) {
        int lo = 0, hi = NN;
        while (lo < hi) {
            int m = (lo + hi) >> 1;
            if (batch[m] < r) lo = m + 1; else hi = m;
        }
        sL[r] = lo;
    }
    __syncthreads();
    if (r >= 2 * GG) return;
    float o0 = 0.f, o1 = 0.f;
    if (r < GG) {
        float c = fmaxf((float)(sL[r + 1] - sL[r]), 1.f);
        float inv = 1.f / c;
        for (int d2 = 0; d2 < DD; ++d2) {
            float v = psum[r * DD + d2] * inv;
            o0 = fmaf(v, lin_w[d2 * 2 + 0], o0);
            o1 = fmaf(v, lin_w[d2 * 2 + 1], o1);
        }
    } else {
        const float* pe = post_emb + (size_t)(r - GG) * DD;
        for (int d2 = 0; d2 < DD; ++d2) {
            float v = pe[d2];
            o0 = fmaf(v, lin_w[d2 * 2 + 0], o0);
            o1 = fmaf(v, lin_w[d2 * 2 + 1], o1);
        }
    }
    out[r * 2 + 0] = o0 + lin_b[0];
    out[r * 2 + 1] = o1 + lin_b[1];
}

// ---------------- host ----------------

extern "C" void kernel_launch(void* const* d_in, const int* in_sizes, int n_in,
                              void* d_out, int out_size, void* d_ws, size_t ws_size,
                              hipStream_t stream) {
    const float* x        = (const float*)d_in[0];
    const int*   ei       = (const int*)d_in[1];
    const int*   src      = ei;
    const int*   dst      = ei + EE;
    const int*   batch    = (const int*)d_in[2];
    const float* post_emb = (const float*)d_in[3];
    const float* Ws[3] = {(const float*)d_in[4],  (const float*)d_in[9],  (const float*)d_in[14]};
    const float* Wd[3] = {(const float*)d_in[5],  (const float*)d_in[10], (const float*)d_in[15]};
    const float* av[3] = {(const float*)d_in[6],  (const float*)d_in[11], (const float*)d_in[16]};
    const float* ad[3] = {(const float*)d_in[7],  (const float*)d_in[12], (const float*)d_in[17]};
    const float* bb[3] = {(const float*)d_in[8],  (const float*)d_in[13], (const float*)d_in[18]};
    const float* lin_w = (const float*)d_in[19];
    const float* lin_b = (const float*)d_in[20];
    float* outp = (float*)d_out;

    char* w = (char*)d_ws;
    size_t off = 0;
    auto alloc = [&](size_t bytes) -> char* {
        char* p = w + off;
        off += (bytes + 255) & ~(size_t)255;
        return p;
    };
    __half*         xs       = (__half*)alloc((size_t)NN * DD * 2);
    __half*         h16      = (__half*)alloc((size_t)NN * DD * 2);
    float*          es       = (float*)alloc((size_t)NN * 4);
    float*          ed       = (float*)alloc((size_t)NN * 4);
    int*            rowstart = (int*)alloc((size_t)(NN + 1) * 4);
    unsigned short* csr      = (unsigned short*)alloc((size_t)EE * 2);
    float*          wdadAll  = (float*)alloc(3 * FF * 4);
    float*          wsasAll  = (float*)alloc(3 * FF * 4);
    float*          psum     = (float*)alloc((size_t)GG * DD * 4);
    unsigned int*   gbuf     = (unsigned int*)alloc((size_t)NBKT * BCAP * 4);
    int*            gcur     = (int*)alloc(256 * 4);

    // ---- init (zeroing + projection vectors) ----
    init_k<<<4, 256, 0, stream>>>(Wd[0], ad[0], Ws[0], av[0],
                                  Wd[1], ad[1], Ws[1], av[1],
                                  Wd[2], ad[2], Ws[2], av[2],
                                  wdadAll, wsasAll, gcur, psum);

    // ---- CSR build: bin (single-read) -> merged build ----
    bin_k<<<NCH, 256, 0, stream>>>(src, dst, gbuf, gcur);
    build_k<<<NBKT, 256, 0, stream>>>(gbuf, gcur, rowstart, csr);

    // ---- 3 GAT layers ----
    const int XB = (NN + 63) / 64;        // 782 blocks: 64 rows per block
    for (int l = 0; l < 3; ++l) {
        if (l == 0)
            xform_k<FF, false><<<XB, 256, 0, stream>>>(x, nullptr, Ws[l],
                                                       wsasAll + l * FF, wdadAll + l * FF,
                                                       xs, es, ed, NN);
        else
            xform_k<DD, true><<<XB, 256, 0, stream>>>(nullptr, h16, Ws[l],
                                                      wsasAll + l * FF, wdadAll + l * FF,
                                                      xs, es, ed, NN);
        agg_k<<<(NN * 64 + 255) / 256, 256, 0, stream>>>(rowstart, csr, xs, es, ed,
                                                         bb[l], h16, NN, (l < 2) ? 1 : 0);
    }

    // ---- pooling + final linear ----
    pool_k<<<((NN + 15) / 16 * 64 + 255) / 256, 256, 0, stream>>>(h16, batch, psum, NN);
    final_k<<<1, 128, 0, stream>>>(psum, batch, post_emb, lin_w, lin_b, outp);
}

// Round 18
// 168.535 us; speedup vs baseline: 1.3161x; 1.0475x over previous
//
#include <hip/hip_runtime.h>
#include <hip/hip_fp16.h>
#include <math.h>

#define NN 50000
#define FF 128
#define DD 64
#define EE 800000
#define GG 64
#define NEG_SLOPE 0.2f
#define EPSV 1e-16f

// CSR-build bucketing: coarse bucket = dst>>8 (256 nodes each)
#define NBKT 196                     // ceil(NN/256)
#define BCAP 5120                    // max edges/bucket (mean 4096, +16 sigma)
#define CHUNK 4096
#define EPB (CHUNK / 256)            // 16 edges per thread
#define NCH ((EE + CHUNK - 1) / CHUNK)   // 196

// ---------------- init: zero gcur/psum + projection vectors ----------------
__global__ __launch_bounds__(256) void init_k(
    const float* __restrict__ Wd0, const float* __restrict__ ad0,
    const float* __restrict__ Ws0, const float* __restrict__ as0,
    const float* __restrict__ Wd1, const float* __restrict__ ad1,
    const float* __restrict__ Ws1, const float* __restrict__ as1,
    const float* __restrict__ Wd2, const float* __restrict__ ad2,
    const float* __restrict__ Ws2, const float* __restrict__ as2,
    float* __restrict__ wdadAll, float* __restrict__ wsasAll,
    int* __restrict__ gcur, float* __restrict__ psum) {
    int b = blockIdx.x;
    int k = threadIdx.x;
    if (b == 3) {
        gcur[k] = 0;
        for (int i = k; i < GG * DD; i += 256) psum[i] = 0.f;
        return;
    }
    const float* Wd = (b == 0) ? Wd0 : (b == 1) ? Wd1 : Wd2;
    const float* ad = (b == 0) ? ad0 : (b == 1) ? ad1 : ad2;
    const float* Ws = (b == 0) ? Ws0 : (b == 1) ? Ws1 : Ws2;
    const float* as = (b == 0) ? as0 : (b == 1) ? as1 : as2;
    int Din = (b == 0) ? FF : DD;
    if (k < Din) {
        float accd = 0.f, accs = 0.f;
        for (int d2 = 0; d2 < DD; ++d2) {
            accd += Wd[k * DD + d2] * ad[d2];
            accs += Ws[k * DD + d2] * as[d2];
        }
        wdadAll[b * FF + k] = accd;
        wsasAll[b * FF + k] = accs;
    }
}

// ---------------- CSR build ----------------

// Single global read pass: each thread holds its 16 edges in registers.
__global__ __launch_bounds__(256) void bin_k(const int* __restrict__ src,
                                             const int* __restrict__ dst,
                                             unsigned int* __restrict__ gbuf,
                                             int* __restrict__ gcur) {
    __shared__ unsigned int staged[CHUNK];     // 16 KB
    __shared__ int bc[256], bs[256], rb[256];
    int tid = threadIdx.x;
    bc[tid] = 0;
    __syncthreads();
    int base = blockIdx.x * CHUNK;
    int cnt = min(CHUNK, EE - base);
    unsigned int pe[EPB];
    int bk[EPB], lofs[EPB];
#pragma unroll
    for (int k = 0; k < EPB; ++k) {
        int i = tid + k * 256;                 // coalesced
        bk[k] = -1;
        if (i < cnt) {
            unsigned int s = (unsigned)src[base + i];
            unsigned int d = (unsigned)dst[base + i];
            pe[k] = (s << 16) | d;
            bk[k] = (int)(d >> 8);
            lofs[k] = atomicAdd(&bc[bk[k]], 1);
        }
    }
    __syncthreads();
    int v = bc[tid];
    bs[tid] = v;
    __syncthreads();
    for (int off = 1; off < 256; off <<= 1) {
        int t = (tid >= off) ? bs[tid - off] : 0;
        __syncthreads();
        bs[tid] += t;
        __syncthreads();
    }
    int excl = bs[tid] - v;
    __syncthreads();
    bs[tid] = excl;
    rb[tid] = atomicAdd(&gcur[tid], v);
    __syncthreads();
#pragma unroll
    for (int k = 0; k < EPB; ++k)
        if (bk[k] >= 0) staged[bs[bk[k]] + lofs[k]] = pe[k];
    __syncthreads();
    for (int i = tid; i < cnt; i += 256) {
        unsigned int p = staged[i];
        int b = (int)((p & 0xFFFFu) >> 8);
        gbuf[(size_t)b * BCAP + rb[b] + (i - bs[b])] = p;
    }
}

// merged bucket-prefix + hist + scan + rowstart + place; csr stored as ushort
__global__ __launch_bounds__(256) void build_k(const unsigned int* __restrict__ gbuf,
                                               const int* __restrict__ gcur,
                                               int* __restrict__ rowstart,
                                               unsigned short* __restrict__ csr) {
    __shared__ unsigned int st[BCAP];          // 20 KB
    __shared__ int hist[256], sc[256], cur[256];
    int tid = threadIdx.x, b = blockIdx.x;

    int gv = (tid < NBKT) ? gcur[tid] : 0;
    sc[tid] = gv;
    __syncthreads();
    for (int off = 1; off < 256; off <<= 1) {
        int t = (tid >= off) ? sc[tid - off] : 0;
        __syncthreads();
        sc[tid] += t;
        __syncthreads();
    }
    int bktoff = sc[b] - gcur[b];              // exclusive prefix at b
    if (b == 0 && tid == 0) rowstart[NN] = EE;
    __syncthreads();

    hist[tid] = 0;
    __syncthreads();
    int nb = gcur[b];
    const unsigned int* bb = gbuf + (size_t)b * BCAP;
    for (int i = tid; i < nb; i += 256) {
        unsigned int p = bb[i];
        st[i] = p;
        atomicAdd(&hist[p & 255u], 1);
    }
    __syncthreads();
    int v = hist[tid];
    sc[tid] = v;
    __syncthreads();
    for (int off = 1; off < 256; off <<= 1) {
        int t = (tid >= off) ? sc[tid - off] : 0;
        __syncthreads();
        sc[tid] += t;
        __syncthreads();
    }
    int rs = bktoff + sc[tid] - v;
    int node = b * 256 + tid;
    if (node < NN) rowstart[node] = rs;
    cur[tid] = rs;
    __syncthreads();
    for (int i = tid; i < nb; i += 256) {
        unsigned int p = st[i];
        int pos = atomicAdd(&cur[p & 255u], 1);
        csr[pos] = (unsigned short)(p >> 16);
    }
}

// ---------------- per-layer kernels ----------------

// xs(fp16) = h @ Ws ; es = h @ (Ws@a_s) ; ed = h @ (Wd@a_d)
template <int DIN, bool HIN>
__global__ __launch_bounds__(256, 4) void xform_k(
    const float* __restrict__ hf, const __half* __restrict__ hh,
    const float* __restrict__ Ws,
    const float* __restrict__ wsas, const float* __restrict__ wdad,
    __half* __restrict__ xs, float* __restrict__ es, float* __restrict__ ed,
    int n) {
    constexpr int PAD = DIN + 4;
    constexpr int XP = 68;
    __shared__ float hL[64 * PAD];
    int tid = threadIdx.x;
    int base = blockIdx.x * 64;

    {
        const int T4 = 64 * DIN / 4;               // groups of 4 elems
        int lim = n - base;
        lim = (lim > 64) ? T4 : lim * (DIN / 4);
        if constexpr (!HIN) {
            const float4* hg = reinterpret_cast<const float4*>(hf + (size_t)base * DIN);
            for (int i = tid; i < T4; i += 256) {
                float4 v = (i < lim) ? hg[i] : make_float4(0.f, 0.f, 0.f, 0.f);
                int r = i / (DIN / 4), c = i % (DIN / 4);
                *reinterpret_cast<float4*>(&hL[r * PAD + c * 4]) = v;
            }
        } else {
            const uint2* hg = reinterpret_cast<const uint2*>(hh + (size_t)base * DIN);
            for (int i = tid; i < T4; i += 256) {
                uint2 u = (i < lim) ? hg[i] : make_uint2(0u, 0u);
                float2 f01 = __half22float2(*reinterpret_cast<__half2*>(&u.x));
                float2 f23 = __half22float2(*reinterpret_cast<__half2*>(&u.y));
                int r = i / (DIN / 4), c = i % (DIN / 4);
                float* p = &hL[r * PAD + c * 4];
                p[0] = f01.x; p[1] = f01.y; p[2] = f23.x; p[3] = f23.y;
            }
        }
    }
    __syncthreads();

    int lane = tid & 63;
    int c0 = __builtin_amdgcn_readfirstlane((tid >> 6) << 4);
    float acc[16];
#pragma unroll
    for (int c = 0; c < 16; ++c) acc[c] = 0.f;
    float eacc = 0.f, dacc = 0.f;

    for (int k = 0; k < DIN; k += 4) {
        float4 hv = *reinterpret_cast<const float4*>(&hL[lane * PAD + k]);
        const float* w0 = Ws + (size_t)(k + 0) * DD + c0;
        const float* w1 = Ws + (size_t)(k + 1) * DD + c0;
        const float* w2 = Ws + (size_t)(k + 2) * DD + c0;
        const float* w3 = Ws + (size_t)(k + 3) * DD + c0;
#pragma unroll
        for (int c = 0; c < 16; ++c) {
            acc[c] = fmaf(hv.x, w0[c], acc[c]);
            acc[c] = fmaf(hv.y, w1[c], acc[c]);
            acc[c] = fmaf(hv.z, w2[c], acc[c]);
            acc[c] = fmaf(hv.w, w3[c], acc[c]);
        }
        eacc = fmaf(hv.x, wsas[k + 0], eacc); eacc = fmaf(hv.y, wsas[k + 1], eacc);
        eacc = fmaf(hv.z, wsas[k + 2], eacc); eacc = fmaf(hv.w, wsas[k + 3], eacc);
        dacc = fmaf(hv.x, wdad[k + 0], dacc); dacc = fmaf(hv.y, wdad[k + 1], dacc);
        dacc = fmaf(hv.z, wdad[k + 2], dacc); dacc = fmaf(hv.w, wdad[k + 3], dacc);
    }

    if ((tid >> 6) == 0 && base + lane < n) {
        es[base + lane] = eacc;
        ed[base + lane] = dacc;
    }
    __syncthreads();
    float* xsL = hL;
#pragma unroll
    for (int c = 0; c < 16; c += 4)
        *reinterpret_cast<float4*>(&xsL[lane * XP + c0 + c]) =
            make_float4(acc[c], acc[c + 1], acc[c + 2], acc[c + 3]);
    __syncthreads();
    {
        for (int i = tid; i < 64 * 16; i += 256) {
            int r = i >> 4, c4 = i & 15;
            if (base + r < n) {
                const float* f = &xsL[r * XP + c4 * 4];
                __half2 a = __floats2half2_rn(f[0], f[1]);
                __half2 b2 = __floats2half2_rn(f[2], f[3]);
                uint2 u;
                u.x = *reinterpret_cast<unsigned int*>(&a);
                u.y = *reinterpret_cast<unsigned int*>(&b2);
                *reinterpret_cast<uint2*>(xs + (size_t)(base + r) * DD + c4 * 4) = u;
            }
        }
    }
}

// one wave per destination node, ONE WAVE PER BLOCK (64-thread blocks):
// grid 50000 blocks -> CU scheduler can pack far more waves/CU than the
// 256-thread-block shape (3 blocks/CU = 12 waves) -- more node chains in
// flight to hide the csr->es->exp->gather latency chain.
__global__ __launch_bounds__(64) void agg_k(
    const int* __restrict__ rowstart, const unsigned short* __restrict__ csr_src,
    const __half* __restrict__ xs, const float* __restrict__ es,
    const float* __restrict__ ed, const float* __restrict__ bias,
    __half* __restrict__ hout, int n, int relu) {
    int wid = blockIdx.x;
    int lane = threadIdx.x;
    if (wid >= n) return;
    int beg = rowstart[wid];
    int deg = rowstart[wid + 1] - beg;
    float edv = ed[wid];
    int slot = lane >> 3;       // 8 parallel edges
    int fl = lane & 7;          // 16B (8-half) feature slice

    float acc[8];
#pragma unroll
    for (int q = 0; q < 8; ++q) acc[q] = 0.f;
    float zl = 0.f;

    for (int c0 = 0; c0 < deg; c0 += 64) {
        int rem = min(64, deg - c0);
        int sv = 0;
        float pv = 0.f;
        if (lane < rem) {
            sv = (int)csr_src[beg + c0 + lane];
            float e = es[sv] + edv;
            e = (e >= 0.f) ? e : NEG_SLOPE * e;
            pv = __expf(e);
        }
        zl += pv;
        int iters = (rem + 7) >> 3;
#pragma unroll 2
        for (int c = 0; c < iters; ++c) {
            int j = c * 8 + slot;                  // < 64 always
            float p = __shfl(pv, j, 64);           // 0 for padding
            int s = __shfl(sv, j, 64);
            uint4 u = *reinterpret_cast<const uint4*>(xs + (size_t)s * DD + fl * 8);
            unsigned int uu[4] = {u.x, u.y, u.z, u.w};
#pragma unroll
            for (int q = 0; q < 4; ++q) {
                float2 f = __half22float2(*reinterpret_cast<const __half2*>(&uu[q]));
                acc[2 * q]     = fmaf(p, f.x, acc[2 * q]);
                acc[2 * q + 1] = fmaf(p, f.y, acc[2 * q + 1]);
            }
        }
    }

#pragma unroll
    for (int off = 32; off; off >>= 1) zl += __shfl_xor(zl, off, 64);
#pragma unroll
    for (int q = 0; q < 8; ++q) {
        acc[q] += __shfl_xor(acc[q], 8, 64);
        acc[q] += __shfl_xor(acc[q], 16, 64);
        acc[q] += __shfl_xor(acc[q], 32, 64);
    }

    if (slot == 0) {            // lanes 0..7; lane fl owns features [fl*8, fl*8+8)
        float inv = 1.f / (zl + EPSV);
        const float4* bp = reinterpret_cast<const float4*>(bias) + fl * 2;
        float4 b0 = bp[0], b1 = bp[1];
        float v0 = fmaf(acc[0], inv, b0.x), v1 = fmaf(acc[1], inv, b0.y);
        float v2 = fmaf(acc[2], inv, b0.z), v3 = fmaf(acc[3], inv, b0.w);
        float v4 = fmaf(acc[4], inv, b1.x), v5 = fmaf(acc[5], inv, b1.y);
        float v6 = fmaf(acc[6], inv, b1.z), v7 = fmaf(acc[7], inv, b1.w);
        if (relu) {
            v0 = fmaxf(v0, 0.f); v1 = fmaxf(v1, 0.f);
            v2 = fmaxf(v2, 0.f); v3 = fmaxf(v3, 0.f);
            v4 = fmaxf(v4, 0.f); v5 = fmaxf(v5, 0.f);
            v6 = fmaxf(v6, 0.f); v7 = fmaxf(v7, 0.f);
        }
        __half2 h0 = __floats2half2_rn(v0, v1);
        __half2 h1 = __floats2half2_rn(v2, v3);
        __half2 h2 = __floats2half2_rn(v4, v5);
        __half2 h3 = __floats2half2_rn(v6, v7);
        uint4 u;
        u.x = *reinterpret_cast<unsigned int*>(&h0);
        u.y = *reinterpret_cast<unsigned int*>(&h1);
        u.z = *reinterpret_cast<unsigned int*>(&h2);
        u.w = *reinterpret_cast<unsigned int*>(&h3);
        *reinterpret_cast<uint4*>(hout + (size_t)wid * DD + fl * 8) = u;
    }
}

// ---------------- pooling + final linear ----------------

// one wave per block (64 threads); wave handles 16 consecutive nodes
__global__ __launch_bounds__(64) void pool_k(
    const __half* __restrict__ h, const int* __restrict__ batch,
    float* __restrict__ psum, int n) {
    int wid = blockIdx.x;
    int lane = threadIdx.x;
    int beg = wid * 16;
    if (beg >= n) return;
    int end = min(beg + 16, n);
    int curg = batch[beg];
    float acc = 0.f;
    for (int i = beg; i < end; ++i) {
        int g = batch[i];
        if (g != curg) {
            atomicAdd(&psum[curg * DD + lane], acc);
            acc = 0.f; curg = g;
        }
        acc += __half2float(h[(size_t)i * DD + lane]);
    }
    atomicAdd(&psum[curg * DD + lane], acc);
}

__global__ void final_k(const float* __restrict__ psum, const int* __restrict__ batch,
                        const float* __restrict__ post_emb,
                        const float* __restrict__ lin_w, const float* __restrict__ lin_b,
                        float* __restrict__ out) {
    __shared__ int sL[GG + 1];
    int r = threadIdx.x;
    if (r <= GG) {
        int lo = 0, hi = NN;
        while (lo < hi) {
            int m = (lo + hi) >> 1;
            if (batch[m] < r) lo = m + 1; else hi = m;
        }
        sL[r] = lo;
    }
    __syncthreads();
    if (r >= 2 * GG) return;
    float o0 = 0.f, o1 = 0.f;
    if (r < GG) {
        float c = fmaxf((float)(sL[r + 1] - sL[r]), 1.f);
        float inv = 1.f / c;
        for (int d2 = 0; d2 < DD; ++d2) {
            float v = psum[r * DD + d2] * inv;
            o0 = fmaf(v, lin_w[d2 * 2 + 0], o0);
            o1 = fmaf(v, lin_w[d2 * 2 + 1], o1);
        }
    } else {
        const float* pe = post_emb + (size_t)(r - GG) * DD;
        for (int d2 = 0; d2 < DD; ++d2) {
            float v = pe[d2];
            o0 = fmaf(v, lin_w[d2 * 2 + 0], o0);
            o1 = fmaf(v, lin_w[d2 * 2 + 1], o1);
        }
    }
    out[r * 2 + 0] = o0 + lin_b[0];
    out[r * 2 + 1] = o1 + lin_b[1];
}

// ---------------- host ----------------

extern "C" void kernel_launch(void* const* d_in, const int* in_sizes, int n_in,
                              void* d_out, int out_size, void* d_ws, size_t ws_size,
                              hipStream_t stream) {
    const float* x        = (const float*)d_in[0];
    const int*   ei       = (const int*)d_in[1];
    const int*   src      = ei;
    const int*   dst      = ei + EE;
    const int*   batch    = (const int*)d_in[2];
    const float* post_emb = (const float*)d_in[3];
    const float* Ws[3] = {(const float*)d_in[4],  (const float*)d_in[9],  (const float*)d_in[14]};
    const float* Wd[3] = {(const float*)d_in[5],  (const float*)d_in[10], (const float*)d_in[15]};
    const float* av[3] = {(const float*)d_in[6],  (const float*)d_in[11], (const float*)d_in[16]};
    const float* ad[3] = {(const float*)d_in[7],  (const float*)d_in[12], (const float*)d_in[17]};
    const float* bb[3] = {(const float*)d_in[8],  (const float*)d_in[13], (const float*)d_in[18]};
    const float* lin_w = (const float*)d_in[19];
    const float* lin_b = (const float*)d_in[20];
    float* outp = (float*)d_out;

    char* w = (char*)d_ws;
    size_t off = 0;
    auto alloc = [&](size_t bytes) -> char* {
        char* p = w + off;
        off += (bytes + 255) & ~(size_t)255;
        return p;
    };
    __half*         xs       = (__half*)alloc((size_t)NN * DD * 2);
    __half*         h16      = (__half*)alloc((size_t)NN * DD * 2);
    float*          es       = (float*)alloc((size_t)NN * 4);
    float*          ed       = (float*)alloc((size_t)NN * 4);
    int*            rowstart = (int*)alloc((size_t)(NN + 1) * 4);
    unsigned short* csr      = (unsigned short*)alloc((size_t)EE * 2);
    float*          wdadAll  = (float*)alloc(3 * FF * 4);
    float*          wsasAll  = (float*)alloc(3 * FF * 4);
    float*          psum     = (float*)alloc((size_t)GG * DD * 4);
    unsigned int*   gbuf     = (unsigned int*)alloc((size_t)NBKT * BCAP * 4);
    int*            gcur     = (int*)alloc(256 * 4);

    // ---- init (zeroing + projection vectors) ----
    init_k<<<4, 256, 0, stream>>>(Wd[0], ad[0], Ws[0], av[0],
                                  Wd[1], ad[1], Ws[1], av[1],
                                  Wd[2], ad[2], Ws[2], av[2],
                                  wdadAll, wsasAll, gcur, psum);

    // ---- CSR build: bin (single-read) -> merged build ----
    bin_k<<<NCH, 256, 0, stream>>>(src, dst, gbuf, gcur);
    build_k<<<NBKT, 256, 0, stream>>>(gbuf, gcur, rowstart, csr);

    // ---- 3 GAT layers ----
    const int XB = (NN + 63) / 64;        // 782 blocks: 64 rows per block
    for (int l = 0; l < 3; ++l) {
        if (l == 0)
            xform_k<FF, false><<<XB, 256, 0, stream>>>(x, nullptr, Ws[l],
                                                       wsasAll + l * FF, wdadAll + l * FF,
                                                       xs, es, ed, NN);
        else
            xform_k<DD, true><<<XB, 256, 0, stream>>>(nullptr, h16, Ws[l],
                                                      wsasAll + l * FF, wdadAll + l * FF,
                                                      xs, es, ed, NN);
        agg_k<<<NN, 64, 0, stream>>>(rowstart, csr, xs, es, ed,
                                     bb[l], h16, NN, (l < 2) ? 1 : 0);
    }

    // ---- pooling + final linear ----
    pool_k<<<(NN + 15) / 16, 64, 0, stream>>>(h16, batch, psum, NN);
    final_k<<<1, 128, 0, stream>>>(psum, batch, post_emb, lin_w, lin_b, outp);
}

// Round 19
// 167.678 us; speedup vs baseline: 1.3228x; 1.0051x over previous
//
#include <hip/hip_runtime.h>
#include <hip/hip_fp16.h>
#include <math.h>

#define NN 50000
#define FF 128
#define DD 64
#define EE 800000
#define GG 64
#define NEG_SLOPE 0.2f
#define EPSV 1e-16f

// CSR-build bucketing: coarse bucket = dst>>8 (256 nodes each)
#define NBKT 196                     // ceil(NN/256)
#define BCAP 5120                    // max edges/bucket (mean 4096, +16 sigma)
#define CHUNK 4096
#define EPB (CHUNK / 256)            // 16 edges per thread
#define NCH ((EE + CHUNK - 1) / CHUNK)   // 196

// wave-shuffle exclusive scan over 256 threads (3 barriers total incl. caller's)
// returns exclusive prefix of v across the block; wsum must be __shared__ int[8]
__device__ __forceinline__ int exscan256(int v, int* wsum) {
    int tid = threadIdx.x;
    int lane = tid & 63, wv = tid >> 6;
    int s = v;
#pragma unroll
    for (int off = 1; off < 64; off <<= 1) {
        int t = __shfl_up(s, off, 64);
        if (lane >= off) s += t;
    }
    if (lane == 63) wsum[wv] = s;
    __syncthreads();
    int wbase = 0;
    if (wv > 0) wbase = wsum[0];
    if (wv > 1) wbase += wsum[1];
    if (wv > 2) wbase += wsum[2];
    return s - v + wbase;
}

// ---------------- init: zero gcur/psum + projection vectors ----------------
__global__ __launch_bounds__(256) void init_k(
    const float* __restrict__ Wd0, const float* __restrict__ ad0,
    const float* __restrict__ Ws0, const float* __restrict__ as0,
    const float* __restrict__ Wd1, const float* __restrict__ ad1,
    const float* __restrict__ Ws1, const float* __restrict__ as1,
    const float* __restrict__ Wd2, const float* __restrict__ ad2,
    const float* __restrict__ Ws2, const float* __restrict__ as2,
    float* __restrict__ wdadAll, float* __restrict__ wsasAll,
    int* __restrict__ gcur, float* __restrict__ psum) {
    int b = blockIdx.x;
    int k = threadIdx.x;
    if (b == 3) {
        gcur[k] = 0;
        for (int i = k; i < GG * DD; i += 256) psum[i] = 0.f;
        return;
    }
    const float* Wd = (b == 0) ? Wd0 : (b == 1) ? Wd1 : Wd2;
    const float* ad = (b == 0) ? ad0 : (b == 1) ? ad1 : ad2;
    const float* Ws = (b == 0) ? Ws0 : (b == 1) ? Ws1 : Ws2;
    const float* as = (b == 0) ? as0 : (b == 1) ? as1 : as2;
    int Din = (b == 0) ? FF : DD;
    if (k < Din) {
        float accd = 0.f, accs = 0.f;
        for (int d2 = 0; d2 < DD; ++d2) {
            accd += Wd[k * DD + d2] * ad[d2];
            accs += Ws[k * DD + d2] * as[d2];
        }
        wdadAll[b * FF + k] = accd;
        wsasAll[b * FF + k] = accs;
    }
}

// ---------------- CSR build ----------------

// Single global read pass; wave-shuffle scan (3 barriers total).
__global__ __launch_bounds__(256) void bin_k(const int* __restrict__ src,
                                             const int* __restrict__ dst,
                                             unsigned int* __restrict__ gbuf,
                                             int* __restrict__ gcur) {
    __shared__ unsigned int staged[CHUNK];     // 16 KB
    __shared__ int bc[256], bs[256], rb[256];
    __shared__ int wsum[8];
    int tid = threadIdx.x;
    bc[tid] = 0;
    __syncthreads();
    int base = blockIdx.x * CHUNK;
    int cnt = min(CHUNK, EE - base);
    unsigned int pe[EPB];
    int bk[EPB], lofs[EPB];
#pragma unroll
    for (int k = 0; k < EPB; ++k) {
        int i = tid + k * 256;                 // coalesced
        bk[k] = -1;
        if (i < cnt) {
            unsigned int s = (unsigned)src[base + i];
            unsigned int d = (unsigned)dst[base + i];
            pe[k] = (s << 16) | d;
            bk[k] = (int)(d >> 8);
            lofs[k] = atomicAdd(&bc[bk[k]], 1);
        }
    }
    __syncthreads();
    int v = bc[tid];
    int excl = exscan256(v, wsum);             // 1 internal barrier
    bs[tid] = excl;
    rb[tid] = atomicAdd(&gcur[tid], v);
    __syncthreads();
#pragma unroll
    for (int k = 0; k < EPB; ++k)
        if (bk[k] >= 0) staged[bs[bk[k]] + lofs[k]] = pe[k];
    __syncthreads();
    for (int i = tid; i < cnt; i += 256) {
        unsigned int p = staged[i];
        int b = (int)((p & 0xFFFFu) >> 8);
        gbuf[(size_t)b * BCAP + rb[b] + (i - bs[b])] = p;
    }
}

// merged bucket-prefix + hist + scan + rowstart + place; csr stored as ushort
__global__ __launch_bounds__(256) void build_k(const unsigned int* __restrict__ gbuf,
                                               const int* __restrict__ gcur,
                                               int* __restrict__ rowstart,
                                               unsigned short* __restrict__ csr) {
    __shared__ unsigned int st[BCAP];          // 20 KB
    __shared__ int hist[256], sc[256], cur[256];
    __shared__ int wsum[8];
    int tid = threadIdx.x, b = blockIdx.x;

    // exclusive prefix over bucket totals -> bktoff for this block
    int gv = (tid < NBKT) ? gcur[tid] : 0;
    int gex = exscan256(gv, wsum);
    sc[tid] = gex;
    if (b == 0 && tid == 0) rowstart[NN] = EE;
    hist[tid] = 0;
    __syncthreads();
    int bktoff = sc[b];

    int nb = gcur[b];
    const unsigned int* bb = gbuf + (size_t)b * BCAP;
    for (int i = tid; i < nb; i += 256) {
        unsigned int p = bb[i];
        st[i] = p;
        atomicAdd(&hist[p & 255u], 1);
    }
    __syncthreads();
    int v = hist[tid];
    int hex = exscan256(v, wsum);
    int rs = bktoff + hex;
    int node = b * 256 + tid;
    if (node < NN) rowstart[node] = rs;
    cur[tid] = rs;
    __syncthreads();
    for (int i = tid; i < nb; i += 256) {
        unsigned int p = st[i];
        int pos = atomicAdd(&cur[p & 255u], 1);
        csr[pos] = (unsigned short)(p >> 16);
    }
}

// ---------------- per-layer kernels ----------------

// xs(fp16) = h @ Ws ; es = h @ (Ws@a_s) ; ed = h @ (Wd@a_d)
template <int DIN, bool HIN>
__global__ __launch_bounds__(256, 4) void xform_k(
    const float* __restrict__ hf, const __half* __restrict__ hh,
    const float* __restrict__ Ws,
    const float* __restrict__ wsas, const float* __restrict__ wdad,
    __half* __restrict__ xs, float* __restrict__ es, float* __restrict__ ed,
    int n) {
    constexpr int PAD = DIN + 4;
    constexpr int XP = 68;
    __shared__ float hL[64 * PAD];
    int tid = threadIdx.x;
    int base = blockIdx.x * 64;

    {
        const int T4 = 64 * DIN / 4;               // groups of 4 elems
        int lim = n - base;
        lim = (lim > 64) ? T4 : lim * (DIN / 4);
        if constexpr (!HIN) {
            const float4* hg = reinterpret_cast<const float4*>(hf + (size_t)base * DIN);
            for (int i = tid; i < T4; i += 256) {
                float4 v = (i < lim) ? hg[i] : make_float4(0.f, 0.f, 0.f, 0.f);
                int r = i / (DIN / 4), c = i % (DIN / 4);
                *reinterpret_cast<float4*>(&hL[r * PAD + c * 4]) = v;
            }
        } else {
            const uint2* hg = reinterpret_cast<const uint2*>(hh + (size_t)base * DIN);
            for (int i = tid; i < T4; i += 256) {
                uint2 u = (i < lim) ? hg[i] : make_uint2(0u, 0u);
                float2 f01 = __half22float2(*reinterpret_cast<__half2*>(&u.x));
                float2 f23 = __half22float2(*reinterpret_cast<__half2*>(&u.y));
                int r = i / (DIN / 4), c = i % (DIN / 4);
                float* p = &hL[r * PAD + c * 4];
                p[0] = f01.x; p[1] = f01.y; p[2] = f23.x; p[3] = f23.y;
            }
        }
    }
    __syncthreads();

    int lane = tid & 63;
    int c0 = __builtin_amdgcn_readfirstlane((tid >> 6) << 4);
    float acc[16];
#pragma unroll
    for (int c = 0; c < 16; ++c) acc[c] = 0.f;
    float eacc = 0.f, dacc = 0.f;

    for (int k = 0; k < DIN; k += 4) {
        float4 hv = *reinterpret_cast<const float4*>(&hL[lane * PAD + k]);
        const float* w0 = Ws + (size_t)(k + 0) * DD + c0;
        const float* w1 = Ws + (size_t)(k + 1) * DD + c0;
        const float* w2 = Ws + (size_t)(k + 2) * DD + c0;
        const float* w3 = Ws + (size_t)(k + 3) * DD + c0;
#pragma unroll
        for (int c = 0; c < 16; ++c) {
            acc[c] = fmaf(hv.x, w0[c], acc[c]);
            acc[c] = fmaf(hv.y, w1[c], acc[c]);
            acc[c] = fmaf(hv.z, w2[c], acc[c]);
            acc[c] = fmaf(hv.w, w3[c], acc[c]);
        }
        eacc = fmaf(hv.x, wsas[k + 0], eacc); eacc = fmaf(hv.y, wsas[k + 1], eacc);
        eacc = fmaf(hv.z, wsas[k + 2], eacc); eacc = fmaf(hv.w, wsas[k + 3], eacc);
        dacc = fmaf(hv.x, wdad[k + 0], dacc); dacc = fmaf(hv.y, wdad[k + 1], dacc);
        dacc = fmaf(hv.z, wdad[k + 2], dacc); dacc = fmaf(hv.w, wdad[k + 3], dacc);
    }

    if ((tid >> 6) == 0 && base + lane < n) {
        es[base + lane] = eacc;
        ed[base + lane] = dacc;
    }
    __syncthreads();
    float* xsL = hL;
#pragma unroll
    for (int c = 0; c < 16; c += 4)
        *reinterpret_cast<float4*>(&xsL[lane * XP + c0 + c]) =
            make_float4(acc[c], acc[c + 1], acc[c + 2], acc[c + 3]);
    __syncthreads();
    {
        for (int i = tid; i < 64 * 16; i += 256) {
            int r = i >> 4, c4 = i & 15;
            if (base + r < n) {
                const float* f = &xsL[r * XP + c4 * 4];
                __half2 a = __floats2half2_rn(f[0], f[1]);
                __half2 b2 = __floats2half2_rn(f[2], f[3]);
                uint2 u;
                u.x = *reinterpret_cast<unsigned int*>(&a);
                u.y = *reinterpret_cast<unsigned int*>(&b2);
                *reinterpret_cast<uint2*>(xs + (size_t)(base + r) * DD + c4 * 4) = u;
            }
        }
    }
}

// one wave per destination node, one wave per block (64-thread blocks).
__global__ __launch_bounds__(64) void agg_k(
    const int* __restrict__ rowstart, const unsigned short* __restrict__ csr_src,
    const __half* __restrict__ xs, const float* __restrict__ es,
    const float* __restrict__ ed, const float* __restrict__ bias,
    __half* __restrict__ hout, int n, int relu) {
    int wid = blockIdx.x;
    int lane = threadIdx.x;
    if (wid >= n) return;
    int beg = rowstart[wid];
    int deg = rowstart[wid + 1] - beg;
    float edv = ed[wid];
    int slot = lane >> 3;       // 8 parallel edges
    int fl = lane & 7;          // 16B (8-half) feature slice

    float acc[8];
#pragma unroll
    for (int q = 0; q < 8; ++q) acc[q] = 0.f;
    float zl = 0.f;

    for (int c0 = 0; c0 < deg; c0 += 64) {
        int rem = min(64, deg - c0);
        int sv = 0;
        float pv = 0.f;
        if (lane < rem) {
            sv = (int)csr_src[beg + c0 + lane];
            float e = es[sv] + edv;
            e = (e >= 0.f) ? e : NEG_SLOPE * e;
            pv = __expf(e);
        }
        zl += pv;
        int iters = (rem + 7) >> 3;
#pragma unroll 2
        for (int c = 0; c < iters; ++c) {
            int j = c * 8 + slot;                  // < 64 always
            float p = __shfl(pv, j, 64);           // 0 for padding
            int s = __shfl(sv, j, 64);
            uint4 u = *reinterpret_cast<const uint4*>(xs + (size_t)s * DD + fl * 8);
            unsigned int uu[4] = {u.x, u.y, u.z, u.w};
#pragma unroll
            for (int q = 0; q < 4; ++q) {
                float2 f = __half22float2(*reinterpret_cast<const __half2*>(&uu[q]));
                acc[2 * q]     = fmaf(p, f.x, acc[2 * q]);
                acc[2 * q + 1] = fmaf(p, f.y, acc[2 * q + 1]);
            }
        }
    }

#pragma unroll
    for (int off = 32; off; off >>= 1) zl += __shfl_xor(zl, off, 64);
#pragma unroll
    for (int q = 0; q < 8; ++q) {
        acc[q] += __shfl_xor(acc[q], 8, 64);
        acc[q] += __shfl_xor(acc[q], 16, 64);
        acc[q] += __shfl_xor(acc[q], 32, 64);
    }

    if (slot == 0) {            // lanes 0..7; lane fl owns features [fl*8, fl*8+8)
        float inv = 1.f / (zl + EPSV);
        const float4* bp = reinterpret_cast<const float4*>(bias) + fl * 2;
        float4 b0 = bp[0], b1 = bp[1];
        float v0 = fmaf(acc[0], inv, b0.x), v1 = fmaf(acc[1], inv, b0.y);
        float v2 = fmaf(acc[2], inv, b0.z), v3 = fmaf(acc[3], inv, b0.w);
        float v4 = fmaf(acc[4], inv, b1.x), v5 = fmaf(acc[5], inv, b1.y);
        float v6 = fmaf(acc[6], inv, b1.z), v7 = fmaf(acc[7], inv, b1.w);
        if (relu) {
            v0 = fmaxf(v0, 0.f); v1 = fmaxf(v1, 0.f);
            v2 = fmaxf(v2, 0.f); v3 = fmaxf(v3, 0.f);
            v4 = fmaxf(v4, 0.f); v5 = fmaxf(v5, 0.f);
            v6 = fmaxf(v6, 0.f); v7 = fmaxf(v7, 0.f);
        }
        __half2 h0 = __floats2half2_rn(v0, v1);
        __half2 h1 = __floats2half2_rn(v2, v3);
        __half2 h2 = __floats2half2_rn(v4, v5);
        __half2 h3 = __floats2half2_rn(v6, v7);
        uint4 u;
        u.x = *reinterpret_cast<unsigned int*>(&h0);
        u.y = *reinterpret_cast<unsigned int*>(&h1);
        u.z = *reinterpret_cast<unsigned int*>(&h2);
        u.w = *reinterpret_cast<unsigned int*>(&h3);
        *reinterpret_cast<uint4*>(hout + (size_t)wid * DD + fl * 8) = u;
    }
}

// ---------------- pooling + final linear ----------------

// one wave per block (64 threads); wave handles 16 consecutive nodes
__global__ __launch_bounds__(64) void pool_k(
    const __half* __restrict__ h, const int* __restrict__ batch,
    float* __restrict__ psum, int n) {
    int wid = blockIdx.x;
    int lane = threadIdx.x;
    int beg = wid * 16;
    if (beg >= n) return;
    int end = min(beg + 16, n);
    int curg = batch[beg];
    float acc = 0.f;
    for (int i = beg; i < end; ++i) {
        int g = batch[i];
        if (g != curg) {
            atomicAdd(&psum[curg * DD + lane], acc);
            acc = 0.f; curg = g;
        }
        acc += __half2float(h[(size_t)i * DD + lane]);
    }
    atomicAdd(&psum[curg * DD + lane], acc);
}

__global__ void final_k(const float* __restrict__ psum, const int* __restrict__ batch,
                        const float* __restrict__ post_emb,
                        const float* __restrict__ lin_w, const float* __restrict__ lin_b,
                        float* __restrict__ out) {
    __shared__ int sL[GG + 1];
    int r = threadIdx.x;
    if (r <= GG) {
        int lo = 0, hi = NN;
        while (lo < hi) {
            int m = (lo + hi) >> 1;
            if (batch[m] < r) lo = m + 1; else hi = m;
        }
        sL[r] = lo;
    }
    __syncthreads();
    if (r >= 2 * GG) return;
    float o0 = 0.f, o1 = 0.f;
    if (r < GG) {
        float c = fmaxf((float)(sL[r + 1] - sL[r]), 1.f);
        float inv = 1.f / c;
        for (int d2 = 0; d2 < DD; ++d2) {
            float v = psum[r * DD + d2] * inv;
            o0 = fmaf(v, lin_w[d2 * 2 + 0], o0);
            o1 = fmaf(v, lin_w[d2 * 2 + 1], o1);
        }
    } else {
        const float* pe = post_emb + (size_t)(r - GG) * DD;
        for (int d2 = 0; d2 < DD; ++d2) {
            float v = pe[d2];
            o0 = fmaf(v, lin_w[d2 * 2 + 0], o0);
            o1 = fmaf(v, lin_w[d2 * 2 + 1], o1);
        }
    }
    out[r * 2 + 0] = o0 + lin_b[0];
    out[r * 2 + 1] = o1 + lin_b[1];
}

// ---------------- host ----------------

extern "C" void kernel_launch(void* const* d_in, const int* in_sizes, int n_in,
                              void* d_out, int out_size, void* d_ws, size_t ws_size,
                              hipStream_t stream) {
    const float* x        = (const float*)d_in[0];
    const int*   ei       = (const int*)d_in[1];
    const int*   src      = ei;
    const int*   dst      = ei + EE;
    const int*   batch    = (const int*)d_in[2];
    const float* post_emb = (const float*)d_in[3];
    const float* Ws[3] = {(const float*)d_in[4],  (const float*)d_in[9],  (const float*)d_in[14]};
    const float* Wd[3] = {(const float*)d_in[5],  (const float*)d_in[10], (const float*)d_in[15]};
    const float* av[3] = {(const float*)d_in[6],  (const float*)d_in[11], (const float*)d_in[16]};
    const float* ad[3] = {(const float*)d_in[7],  (const float*)d_in[12], (const float*)d_in[17]};
    const float* bb[3] = {(const float*)d_in[8],  (const float*)d_in[13], (const float*)d_in[18]};
    const float* lin_w = (const float*)d_in[19];
    const float* lin_b = (const float*)d_in[20];
    float* outp = (float*)d_out;

    char* w = (char*)d_ws;
    size_t off = 0;
    auto alloc = [&](size_t bytes) -> char* {
        char* p = w + off;
        off += (bytes + 255) & ~(size_t)255;
        return p;
    };
    __half*         xs       = (__half*)alloc((size_t)NN * DD * 2);
    __half*         h16      = (__half*)alloc((size_t)NN * DD * 2);
    float*          es       = (float*)alloc((size_t)NN * 4);
    float*          ed       = (float*)alloc((size_t)NN * 4);
    int*            rowstart = (int*)alloc((size_t)(NN + 1) * 4);
    unsigned short* csr      = (unsigned short*)alloc((size_t)EE * 2);
    float*          wdadAll  = (float*)alloc(3 * FF * 4);
    float*          wsasAll  = (float*)alloc(3 * FF * 4);
    float*          psum     = (float*)alloc((size_t)GG * DD * 4);
    unsigned int*   gbuf     = (unsigned int*)alloc((size_t)NBKT * BCAP * 4);
    int*            gcur     = (int*)alloc(256 * 4);

    // ---- init (zeroing + projection vectors) ----
    init_k<<<4, 256, 0, stream>>>(Wd[0], ad[0], Ws[0], av[0],
                                  Wd[1], ad[1], Ws[1], av[1],
                                  Wd[2], ad[2], Ws[2], av[2],
                                  wdadAll, wsasAll, gcur, psum);

    // ---- CSR build: bin (single-read) -> merged build ----
    bin_k<<<NCH, 256, 0, stream>>>(src, dst, gbuf, gcur);
    build_k<<<NBKT, 256, 0, stream>>>(gbuf, gcur, rowstart, csr);

    // ---- 3 GAT layers ----
    const int XB = (NN + 63) / 64;        // 782 blocks: 64 rows per block
    for (int l = 0; l < 3; ++l) {
        if (l == 0)
            xform_k<FF, false><<<XB, 256, 0, stream>>>(x, nullptr, Ws[l],
                                                       wsasAll + l * FF, wdadAll + l * FF,
                                                       xs, es, ed, NN);
        else
            xform_k<DD, true><<<XB, 256, 0, stream>>>(nullptr, h16, Ws[l],
                                                      wsasAll + l * FF, wdadAll + l * FF,
                                                      xs, es, ed, NN);
        agg_k<<<NN, 64, 0, stream>>>(rowstart, csr, xs, es, ed,
                                     bb[l], h16, NN, (l < 2) ? 1 : 0);
    }

    // ---- pooling + final linear ----
    pool_k<<<(NN + 15) / 16, 64, 0, stream>>>(h16, batch, psum, NN);
    final_k<<<1, 128, 0, stream>>>(psum, batch, post_emb, lin_w, lin_b, outp);
}